// Round 1
// baseline (151.583 us; speedup 1.0000x reference)
//
#include <hip/hip_runtime.h>

// ForwardDistance: out[b,n,m] = sum_a agg[a] * tanh(datalin[b,n,a] + critlin[b,m,a])
//   datalin = data @ Wl + bl ; critlin = crit @ Wr + br
// Identity: tanh(x+y) = 1 - 2/(1 + e^{2x} e^{2y})
// Phase 1: fp32 GEMM (vector ALU; no fp32 MFMA on CDNA4) fused with exp epilogue,
//          stores Ed^T [A][2048] and Ec^T [A][2048] in d_ws (4 MB total).
// Phase 2: per (b, n-tile, m-tile, a-half): stage Ed/Ec tiles in LDS (a-major),
//          inner loop = fma + v_rcp_f32 + fma per element; atomicAdd the halves.

#define A_DIM 256
#define K_DIM 512
#define NROWS 2048   // B*N == B*M rows per source

__global__ __launch_bounds__(256) void proj_exp_kernel(
    const float* __restrict__ data, const float* __restrict__ crit,
    const float* __restrict__ Wl, const float* __restrict__ bl,
    const float* __restrict__ Wr, const float* __restrict__ br,
    float* __restrict__ ws)
{
    const int t  = threadIdx.x;
    const int tx = t & 15;                 // a-col group (4 cols)
    const int ty = t >> 4;                 // row group (4 rows)
    const int c0 = blockIdx.x * 64;        // a-col tile base
    const int rowBase = blockIdx.y * 64;   // combined row tile base (0..4095)
    const int src = rowBase >> 11;         // 0 => data/Wl/bl, 1 => crit/Wr/br
    const int lr0 = rowBase & 2047;        // row within source

    const float* X    = src ? crit : data;
    const float* W    = src ? Wr   : Wl;
    const float* bias = src ? br   : bl;
    float* ET = ws + (size_t)src * ((size_t)A_DIM * NROWS);

    __shared__ __align__(16) float As[16][68];  // [k][row], pad 68: write conflicts 2-way (free)
    __shared__ __align__(16) float Bs[16][64];  // [k][col]

    float acc[4][4];
#pragma unroll
    for (int i = 0; i < 4; i++)
#pragma unroll
        for (int j = 0; j < 4; j++) acc[i][j] = 0.f;

    const int ai = t >> 2;          // 0..63 tile row for A staging
    const int ak = (t & 3) * 4;     // k segment for A staging
    const int bk = t >> 4;          // 0..15 k row for B staging
    const int bj = (t & 15) * 4;    // col segment for B staging

    for (int k0 = 0; k0 < K_DIM; k0 += 16) {
        float4 av = *(const float4*)(X + (size_t)(lr0 + ai) * K_DIM + k0 + ak);
        float4 bv = *(const float4*)(W + (size_t)(k0 + bk) * A_DIM + c0 + bj);
        __syncthreads();            // previous iter's LDS reads complete
        As[ak + 0][ai] = av.x; As[ak + 1][ai] = av.y;
        As[ak + 2][ai] = av.z; As[ak + 3][ai] = av.w;
        *(float4*)&Bs[bk][bj] = bv;
        __syncthreads();
#pragma unroll
        for (int kk = 0; kk < 16; kk++) {
            float4 a4 = *(const float4*)&As[kk][ty * 4];
            float4 b4 = *(const float4*)&Bs[kk][tx * 4];
            const float aa[4] = {a4.x, a4.y, a4.z, a4.w};
            const float bb[4] = {b4.x, b4.y, b4.z, b4.w};
#pragma unroll
            for (int i = 0; i < 4; i++)
#pragma unroll
                for (int j = 0; j < 4; j++)
                    acc[i][j] = fmaf(aa[i], bb[j], acc[i][j]);
        }
    }

    // epilogue: E = exp2( clamp( 2*log2(e) * (acc + bias) ) ), store transposed [a][row]
    const float c2 = 2.8853900817779268f;  // 2*log2(e)
#pragma unroll
    for (int j = 0; j < 4; j++) {
        const int aCol = c0 + tx * 4 + j;
        const float b = bias[aCol];
        float4 ev;
        float* pv = &ev.x;
#pragma unroll
        for (int i = 0; i < 4; i++) {
            float v = (acc[i][j] + b) * c2;
            v = fminf(fmaxf(v, -60.f), 60.f);   // never active for this data; overflow guard
            pv[i] = exp2f(v);
        }
        *(float4*)(ET + (size_t)aCol * NROWS + lr0 + ty * 4) = ev;
    }
}

__global__ __launch_bounds__(256) void tanh_reduce_kernel(
    const float* __restrict__ ws, const float* __restrict__ agg,
    float* __restrict__ out)
{
    const int t  = threadIdx.x;
    const int tx = t & 15;              // m group (4 m's)
    const int ty = t >> 4;              // n group (4 n's)
    const int m0 = blockIdx.x * 64;
    const int n0 = blockIdx.y * 64;
    const int b    = blockIdx.z >> 1;
    const int half = blockIdx.z & 1;    // a-range split across blocks for occupancy

    const float* EdT = ws;                                  // [A][2048]
    const float* EcT = ws + (size_t)A_DIM * NROWS;          // [A][2048]
    const int row_n = b * 512 + n0;
    const int row_m = b * 512 + m0;

    __shared__ __align__(16) float Et [64][68];  // [a][n], stride 68 keeps b128 reads aligned
    __shared__ __align__(16) float Ect[64][68];  // [a][m]
    __shared__ __align__(16) float aggs[64];     // 2*agg[a]

    float acc[4][4];
#pragma unroll
    for (int i = 0; i < 4; i++)
#pragma unroll
        for (int j = 0; j < 4; j++) acc[i][j] = 0.f;
    float sagg = 0.f;

    for (int chunk = 0; chunk < 2; chunk++) {
        const int a0 = half * 128 + chunk * 64;
        __syncthreads();
#pragma unroll
        for (int rep = 0; rep < 4; rep++) {
            const int aL  = rep * 16 + (t >> 4);
            const int seg = (t & 15) * 4;
            *(float4*)&Et [aL][seg] = *(const float4*)(EdT + (size_t)(a0 + aL) * NROWS + row_n + seg);
            *(float4*)&Ect[aL][seg] = *(const float4*)(EcT + (size_t)(a0 + aL) * NROWS + row_m + seg);
        }
        if (t < 64) aggs[t] = 2.0f * agg[a0 + t];
        __syncthreads();

        for (int aL = 0; aL < 64; aL += 4) {
            float4 ag4 = *(const float4*)&aggs[aL];
            sagg += (ag4.x + ag4.y) + (ag4.z + ag4.w);
            const float agv[4] = {ag4.x, ag4.y, ag4.z, ag4.w};
#pragma unroll
            for (int u = 0; u < 4; u++) {
                float4 e4 = *(const float4*)&Et [aL + u][ty * 4];
                float4 c4 = *(const float4*)&Ect[aL + u][tx * 4];
                const float ed[4] = {e4.x, e4.y, e4.z, e4.w};
                const float ec[4] = {c4.x, c4.y, c4.z, c4.w};
#pragma unroll
                for (int i = 0; i < 4; i++)
#pragma unroll
                    for (int j = 0; j < 4; j++) {
                        float p = fmaf(ed[i], ec[j], 1.0f);       // 1 + e^{2x}e^{2y}
                        float r = __builtin_amdgcn_rcpf(p);       // raw v_rcp_f32 (~1 ulp)
                        acc[i][j] = fmaf(agv[u], r, acc[i][j]);   // += 2*agg*r
                    }
            }
        }
    }

    // out_partial = sum_{a in half} agg[a] - acc   (tanh = 1 - 2r)
    const float base = 0.5f * sagg;
#pragma unroll
    for (int i = 0; i < 4; i++) {
        const int n = n0 + ty * 4 + i;
        float* orow = out + ((size_t)b * 512 + n) * 512 + m0 + tx * 4;
#pragma unroll
        for (int j = 0; j < 4; j++)
            unsafeAtomicAdd(orow + j, base - acc[i][j]);
    }
}

extern "C" void kernel_launch(void* const* d_in, const int* in_sizes, int n_in,
                              void* d_out, int out_size, void* d_ws, size_t ws_size,
                              hipStream_t stream) {
    const float* data = (const float*)d_in[0];
    const float* crit = (const float*)d_in[1];
    const float* Wl   = (const float*)d_in[2];
    const float* bl   = (const float*)d_in[3];
    const float* Wr   = (const float*)d_in[4];
    const float* br   = (const float*)d_in[5];
    const float* agg  = (const float*)d_in[6];
    float* out = (float*)d_out;
    float* ws  = (float*)d_ws;   // needs 2 * 256 * 2048 * 4 B = 4 MB

    // output accumulated via atomics from the two a-halves -> zero it first
    hipMemsetAsync(d_out, 0, (size_t)out_size * sizeof(float), stream);

    // Phase 1: both projections in one launch; rows 0..2047 = data, 2048..4095 = crit
    proj_exp_kernel<<<dim3(4, 64), 256, 0, stream>>>(data, crit, Wl, bl, Wr, br, ws);

    // Phase 2: grid = (m-tiles, n-tiles, b*2 + a-half) = 8*8*8 = 512 blocks
    tanh_reduce_kernel<<<dim3(8, 8, 8), 256, 0, stream>>>(ws, agg, out);
}